// Round 1
// baseline (217.494 us; speedup 1.0000x reference)
//
#include <hip/hip_runtime.h>
#include <math.h>

#define F 1024
#define D 64
#define H 128

// Prep: A[i][k] = sum_r node[i][r]*W1[r][k] + b1[k]
//       Bt[k][i] = sum_r node[i][r]*W1[64+r][k]   (transposed for coalesced hot-loop reads)
__global__ __launch_bounds__(128) void prep_kernel(
    const float* __restrict__ node, const float* __restrict__ W1,
    const float* __restrict__ b1,
    float* __restrict__ A, float* __restrict__ Bt) {
  const int i = blockIdx.x;
  const int k = threadIdx.x;  // 0..127
  __shared__ float n[D];
  if (k < D) n[k] = node[i * D + k];
  __syncthreads();
  float a = b1[k];
  float b = 0.f;
#pragma unroll
  for (int r = 0; r < D; ++r) {
    const float nv = n[r];
    a = fmaf(nv, W1[r * H + k], a);
    b = fmaf(nv, W1[(D + r) * H + k], b);
  }
  A[i * H + k] = a;
  Bt[k * F + i] = b;
}

// Pair kernel: block b owns rows i0..i0+3; thread owns j = 4*tid..4*tid+3.
// logits[i,j] = sum_k 0.5*w2[k] * x * (1 + erf(x/sqrt(2))), x = A[i,k]+Bt[k,j]
// (b2 is uniform across j -> cancels in softmax, omitted)
__global__ __launch_bounds__(256) void pair_kernel(
    const float* __restrict__ A, const float* __restrict__ Bt,
    const float* __restrict__ w2, float* __restrict__ out) {
  const int i0 = blockIdx.x * 4;
  const int tid = threadIdx.x;

  __shared__ float4 sA[H];   // per-k: A values for the 4 rows
  __shared__ float sW[H];    // 0.5 * w2[k]
  __shared__ float redm[4][4];
  __shared__ float reds[4][4];

  if (tid < H) {
    sA[tid] = make_float4(A[(i0 + 0) * H + tid], A[(i0 + 1) * H + tid],
                          A[(i0 + 2) * H + tid], A[(i0 + 3) * H + tid]);
    sW[tid] = 0.5f * w2[tid];
  }
  __syncthreads();

  float acc[4][4] = {{0.f, 0.f, 0.f, 0.f},
                     {0.f, 0.f, 0.f, 0.f},
                     {0.f, 0.f, 0.f, 0.f},
                     {0.f, 0.f, 0.f, 0.f}};

  const float4* bp = reinterpret_cast<const float4*>(Bt) + tid;  // Bt[k][4*tid..]
#pragma unroll 2
  for (int k = 0; k < H; ++k) {
    const float4 b4 = bp[k * (F / 4)];
    const float4 av = sA[k];
    const float wk = sW[k];
    const float aa[4] = {av.x, av.y, av.z, av.w};
    const float bb[4] = {b4.x, b4.y, b4.z, b4.w};
#pragma unroll
    for (int r = 0; r < 4; ++r) {
#pragma unroll
      for (int m = 0; m < 4; ++m) {
        const float x = aa[r] + bb[m];
        const float e = erff(x * 0.70710678118654752f);
        const float t = wk * x;
        acc[r][m] = fmaf(t, 1.f + e, acc[r][m]);
      }
    }
  }

  // ---- fused softmax over j (1024 per row), rows i0..i0+3 ----
  const int wave = tid >> 6;
  const int lane = tid & 63;

  // row maxes
  float mx[4];
#pragma unroll
  for (int r = 0; r < 4; ++r) {
    float m = fmaxf(fmaxf(acc[r][0], acc[r][1]), fmaxf(acc[r][2], acc[r][3]));
#pragma unroll
    for (int off = 32; off >= 1; off >>= 1)
      m = fmaxf(m, __shfl_xor(m, off, 64));
    mx[r] = m;
  }
  if (lane == 0) {
#pragma unroll
    for (int r = 0; r < 4; ++r) redm[wave][r] = mx[r];
  }
  __syncthreads();
#pragma unroll
  for (int r = 0; r < 4; ++r)
    mx[r] = fmaxf(fmaxf(redm[0][r], redm[1][r]), fmaxf(redm[2][r], redm[3][r]));

  // exp + row sums
  float sm[4];
#pragma unroll
  for (int r = 0; r < 4; ++r) {
    float s = 0.f;
#pragma unroll
    for (int m = 0; m < 4; ++m) {
      acc[r][m] = __expf(acc[r][m] - mx[r]);
      s += acc[r][m];
    }
#pragma unroll
    for (int off = 32; off >= 1; off >>= 1)
      s += __shfl_xor(s, off, 64);
    sm[r] = s;
  }
  if (lane == 0) {
#pragma unroll
    for (int r = 0; r < 4; ++r) reds[wave][r] = sm[r];
  }
  __syncthreads();
#pragma unroll
  for (int r = 0; r < 4; ++r)
    sm[r] = reds[0][r] + reds[1][r] + reds[2][r] + reds[3][r];

  // normalize + store (float4, coalesced)
#pragma unroll
  for (int r = 0; r < 4; ++r) {
    const float inv = 1.f / sm[r];
    float4 o;
    o.x = acc[r][0] * inv;
    o.y = acc[r][1] * inv;
    o.z = acc[r][2] * inv;
    o.w = acc[r][3] * inv;
    *reinterpret_cast<float4*>(out + (size_t)(i0 + r) * F + 4 * tid) = o;
  }
}

extern "C" void kernel_launch(void* const* d_in, const int* in_sizes, int n_in,
                              void* d_out, int out_size, void* d_ws, size_t ws_size,
                              hipStream_t stream) {
  const float* node = (const float*)d_in[0];  // [1024,64]
  const float* W1   = (const float*)d_in[1];  // [128,128]
  const float* b1   = (const float*)d_in[2];  // [128]
  const float* w2   = (const float*)d_in[3];  // [128]
  // d_in[4] = b2 : cancels in softmax, unused
  float* out = (float*)d_out;                 // [1024,1024]

  float* A  = (float*)d_ws;                   // [1024][128] = 512 KB
  float* Bt = A + (size_t)F * H;              // [128][1024] = 512 KB

  prep_kernel<<<F, H, 0, stream>>>(node, W1, b1, A, Bt);
  pair_kernel<<<F / 4, 256, 0, stream>>>(A, Bt, w2, out);
}

// Round 2
// 115.191 us; speedup vs baseline: 1.8881x; 1.8881x over previous
//
#include <hip/hip_runtime.h>
#include <math.h>

#define F 1024
#define D 64
#define H 128

// Prep: A[i][k] = sum_r node[i][r]*W1[r][k] + b1[k]
//       Bt[k][i] = sum_r node[i][r]*W1[64+r][k]   (transposed for coalesced hot-loop reads)
__global__ __launch_bounds__(128) void prep_kernel(
    const float* __restrict__ node, const float* __restrict__ W1,
    const float* __restrict__ b1,
    float* __restrict__ A, float* __restrict__ Bt) {
  const int i = blockIdx.x;
  const int k = threadIdx.x;  // 0..127
  __shared__ float n[D];
  if (k < D) n[k] = node[i * D + k];
  __syncthreads();
  float a = b1[k];
  float b = 0.f;
#pragma unroll
  for (int r = 0; r < D; ++r) {
    const float nv = n[r];
    a = fmaf(nv, W1[r * H + k], a);
    b = fmaf(nv, W1[(D + r) * H + k], b);
  }
  A[i * H + k] = a;
  Bt[k * F + i] = b;
}

// Pair kernel: block = one output row i; thread owns j = 4*tid..4*tid+3.
// logits[i,j] = sum_k 0.5*w2[k] * x * (1 + erf(x/sqrt(2))), x = A[i,k]+Bt[k,j]
// (b2 is uniform across j -> cancels in softmax, omitted)
__global__ __launch_bounds__(256) void pair_kernel(
    const float* __restrict__ A, const float* __restrict__ Bt,
    const float* __restrict__ w2, float* __restrict__ out) {
  const int i = blockIdx.x;
  const int tid = threadIdx.x;

  __shared__ float sA[H];  // A[i][k]
  __shared__ float sW[H];  // 0.5 * w2[k]
  __shared__ float redm[4];
  __shared__ float reds[4];

  if (tid < H) {
    sA[tid] = A[i * H + tid];
    sW[tid] = 0.5f * w2[tid];
  }
  __syncthreads();

  float acc0 = 0.f, acc1 = 0.f, acc2 = 0.f, acc3 = 0.f;

  const float4* bp = reinterpret_cast<const float4*>(Bt) + tid;  // Bt[k][4*tid..]
#pragma unroll 4
  for (int k = 0; k < H; ++k) {
    const float4 b4 = bp[k * (F / 4)];
    const float a = sA[k];
    const float wk = sW[k];
    {
      const float x = a + b4.x;
      acc0 = fmaf(wk * x, 1.f + erff(x * 0.70710678118654752f), acc0);
    }
    {
      const float x = a + b4.y;
      acc1 = fmaf(wk * x, 1.f + erff(x * 0.70710678118654752f), acc1);
    }
    {
      const float x = a + b4.z;
      acc2 = fmaf(wk * x, 1.f + erff(x * 0.70710678118654752f), acc2);
    }
    {
      const float x = a + b4.w;
      acc3 = fmaf(wk * x, 1.f + erff(x * 0.70710678118654752f), acc3);
    }
  }

  // ---- fused softmax over the row (1024 logits) ----
  const int wave = tid >> 6;
  const int lane = tid & 63;

  float m = fmaxf(fmaxf(acc0, acc1), fmaxf(acc2, acc3));
#pragma unroll
  for (int off = 32; off >= 1; off >>= 1)
    m = fmaxf(m, __shfl_xor(m, off, 64));
  if (lane == 0) redm[wave] = m;
  __syncthreads();
  m = fmaxf(fmaxf(redm[0], redm[1]), fmaxf(redm[2], redm[3]));

  acc0 = __expf(acc0 - m);
  acc1 = __expf(acc1 - m);
  acc2 = __expf(acc2 - m);
  acc3 = __expf(acc3 - m);
  float s = acc0 + acc1 + acc2 + acc3;
#pragma unroll
  for (int off = 32; off >= 1; off >>= 1)
    s += __shfl_xor(s, off, 64);
  if (lane == 0) reds[wave] = s;
  __syncthreads();
  s = reds[0] + reds[1] + reds[2] + reds[3];

  const float inv = 1.f / s;
  float4 o;
  o.x = acc0 * inv;
  o.y = acc1 * inv;
  o.z = acc2 * inv;
  o.w = acc3 * inv;
  *reinterpret_cast<float4*>(out + (size_t)i * F + 4 * tid) = o;
}

extern "C" void kernel_launch(void* const* d_in, const int* in_sizes, int n_in,
                              void* d_out, int out_size, void* d_ws, size_t ws_size,
                              hipStream_t stream) {
  const float* node = (const float*)d_in[0];  // [1024,64]
  const float* W1   = (const float*)d_in[1];  // [128,128]
  const float* b1   = (const float*)d_in[2];  // [128]
  const float* w2   = (const float*)d_in[3];  // [128]
  // d_in[4] = b2 : cancels in softmax, unused
  float* out = (float*)d_out;                 // [1024,1024]

  float* A  = (float*)d_ws;                   // [1024][128] = 512 KB
  float* Bt = A + (size_t)F * H;              // [128][1024] = 512 KB

  prep_kernel<<<F, H, 0, stream>>>(node, W1, b1, A, Bt);
  pair_kernel<<<F, 256, 0, stream>>>(A, Bt, w2, out);
}

// Round 3
// 49.204 us; speedup vs baseline: 4.4202x; 2.3411x over previous
//
#include <hip/hip_runtime.h>
#include <math.h>

#define F 1024
#define D 64
#define H 128

// Prep: A[i][k] = sum_r node[i][r]*W1[r][k] + b1[k]
//       Bt[k][i] = sum_r node[i][r]*W1[64+r][k]   (transposed for coalesced hot-loop reads)
__global__ __launch_bounds__(128) void prep_kernel(
    const float* __restrict__ node, const float* __restrict__ W1,
    const float* __restrict__ b1,
    float* __restrict__ A, float* __restrict__ Bt) {
  const int i = blockIdx.x;
  const int k = threadIdx.x;  // 0..127
  __shared__ float n[D];
  if (k < D) n[k] = node[i * D + k];
  __syncthreads();
  float a = b1[k];
  float b = 0.f;
#pragma unroll
  for (int r = 0; r < D; ++r) {
    const float nv = n[r];
    a = fmaf(nv, W1[r * H + k], a);
    b = fmaf(nv, W1[(D + r) * H + k], b);
  }
  A[i * H + k] = a;
  Bt[k * F + i] = b;
}

// Pair kernel: block = one output row i; thread owns j = 4*tid..4*tid+3.
// gelu_tanh(x) = x * sigmoid(1.59577*(x + 0.044715 x^3))
//             = x * rcp(1 + exp2(x * (C1 + C2*x^2)))
// with C1 = -2*sqrt(2/pi)*log2(e), C2 = C1*0.044715  (all constants folded).
// logits[i,j] = sum_k w2[k] * gelu(A[i,k] + Bt[k,j]); b2 cancels in softmax.
#define C1 (-2.3022082f)
#define C2 (-0.10294323f)

__global__ __launch_bounds__(256) void pair_kernel(
    const float* __restrict__ A, const float* __restrict__ Bt,
    const float* __restrict__ w2, float* __restrict__ out) {
  const int i = blockIdx.x;
  const int tid = threadIdx.x;

  __shared__ float sA[H];  // A[i][k]
  __shared__ float sW[H];  // w2[k]
  __shared__ float redm[4];
  __shared__ float reds[4];

  if (tid < H) {
    sA[tid] = A[i * H + tid];
    sW[tid] = w2[tid];
  }
  __syncthreads();

  float acc0 = 0.f, acc1 = 0.f, acc2 = 0.f, acc3 = 0.f;

  const float4* bp = reinterpret_cast<const float4*>(Bt) + tid;  // Bt[k][4*tid..]
#pragma unroll 4
  for (int k = 0; k < H; ++k) {
    const float4 b4 = bp[k * (F / 4)];
    const float a = sA[k];
    const float wk = sW[k];
    {
      const float x = a + b4.x;
      const float arg = x * fmaf(C2, x * x, C1);
      const float r = __builtin_amdgcn_rcpf(1.f + __builtin_amdgcn_exp2f(arg));
      acc0 = fmaf(wk * x, r, acc0);
    }
    {
      const float x = a + b4.y;
      const float arg = x * fmaf(C2, x * x, C1);
      const float r = __builtin_amdgcn_rcpf(1.f + __builtin_amdgcn_exp2f(arg));
      acc1 = fmaf(wk * x, r, acc1);
    }
    {
      const float x = a + b4.z;
      const float arg = x * fmaf(C2, x * x, C1);
      const float r = __builtin_amdgcn_rcpf(1.f + __builtin_amdgcn_exp2f(arg));
      acc2 = fmaf(wk * x, r, acc2);
    }
    {
      const float x = a + b4.w;
      const float arg = x * fmaf(C2, x * x, C1);
      const float r = __builtin_amdgcn_rcpf(1.f + __builtin_amdgcn_exp2f(arg));
      acc3 = fmaf(wk * x, r, acc3);
    }
  }

  // ---- fused softmax over the row (1024 logits) ----
  const int wave = tid >> 6;
  const int lane = tid & 63;

  float m = fmaxf(fmaxf(acc0, acc1), fmaxf(acc2, acc3));
#pragma unroll
  for (int off = 32; off >= 1; off >>= 1)
    m = fmaxf(m, __shfl_xor(m, off, 64));
  if (lane == 0) redm[wave] = m;
  __syncthreads();
  m = fmaxf(fmaxf(redm[0], redm[1]), fmaxf(redm[2], redm[3]));

  acc0 = __expf(acc0 - m);
  acc1 = __expf(acc1 - m);
  acc2 = __expf(acc2 - m);
  acc3 = __expf(acc3 - m);
  float s = acc0 + acc1 + acc2 + acc3;
#pragma unroll
  for (int off = 32; off >= 1; off >>= 1)
    s += __shfl_xor(s, off, 64);
  if (lane == 0) reds[wave] = s;
  __syncthreads();
  s = reds[0] + reds[1] + reds[2] + reds[3];

  const float inv = __builtin_amdgcn_rcpf(s);
  float4 o;
  o.x = acc0 * inv;
  o.y = acc1 * inv;
  o.z = acc2 * inv;
  o.w = acc3 * inv;
  *reinterpret_cast<float4*>(out + (size_t)i * F + 4 * tid) = o;
}

extern "C" void kernel_launch(void* const* d_in, const int* in_sizes, int n_in,
                              void* d_out, int out_size, void* d_ws, size_t ws_size,
                              hipStream_t stream) {
  const float* node = (const float*)d_in[0];  // [1024,64]
  const float* W1   = (const float*)d_in[1];  // [128,128]
  const float* b1   = (const float*)d_in[2];  // [128]
  const float* w2   = (const float*)d_in[3];  // [128]
  // d_in[4] = b2 : cancels in softmax, unused
  float* out = (float*)d_out;                 // [1024,1024]

  float* A  = (float*)d_ws;                   // [1024][128] = 512 KB
  float* Bt = A + (size_t)F * H;              // [128][1024] = 512 KB

  prep_kernel<<<F, H, 0, stream>>>(node, W1, b1, A, Bt);
  pair_kernel<<<F, 256, 0, stream>>>(A, Bt, w2, out);
}